// Round 6
// baseline (455.601 us; speedup 1.0000x reference)
//
#include <hip/hip_runtime.h>
#include <hip/hip_bf16.h>
#include <math.h>

// Shapes (fixed by the problem)
#define BB   512
#define NN   64
#define NFG  1024
#define NFR  256
#define MM   (BB * NN)          // 32768
#define RG_OFF 33554432L        // out elements before relation_graph

typedef __attribute__((ext_vector_type(8))) short bf16x8;   // 8 bf16 = 4 VGPRs
typedef __attribute__((ext_vector_type(4))) float f32x4;
typedef __attribute__((ext_vector_type(8))) unsigned short u16x8;
typedef __attribute__((ext_vector_type(4))) unsigned short u16x4;

__device__ inline unsigned short f2bf(float f) {
    union { float f; unsigned u; } v; v.f = f;
    unsigned u = v.u;
    return (unsigned short)((u + 0x7FFFu + ((u >> 16) & 1u)) >> 16);  // RNE
}

__device__ inline void gld_lds16(const unsigned short* g, unsigned short* l) {
    // async global->LDS, 16B per lane; LDS dst is wave-uniform base + lane*16
    __builtin_amdgcn_global_load_lds((const __attribute__((address_space(1))) void*)g,
                                     (__attribute__((address_space(3))) void*)l, 16, 0, 0);
}

// intra-wave LDS handoff fence (r4: zero-barrier fused)
__device__ inline void wave_fence() {
    asm volatile("" ::: "memory");
    __builtin_amdgcn_wave_barrier();
    __builtin_amdgcn_sched_barrier(0);
}

// ---------------- prep: dual cast (+transpose) + weight transposes + bias ----------------
// block roles: [0,8192) feats 64x64 tile -> featsb (row-major) AND featsbT (transposed);
// [8192,8448) W_theta^T; [8448,8704) W_phi^T; [8704,9728) W_gcn^T; [9728] bias.

__device__ void tcast_body(const float* __restrict__ in, unsigned short* __restrict__ out,
                           int K, int N, int bx, int by, float tile[32][33]) {
    const int t  = threadIdx.x;
    const int tx = t & 31, ty = t >> 5;
    const int k0 = by * 32, n0 = bx * 32;
#pragma unroll
    for (int r = 0; r < 4; ++r)
        tile[ty + r * 8][tx] = in[(long)(k0 + ty + r * 8) * N + n0 + tx];
    __syncthreads();
#pragma unroll
    for (int r = 0; r < 4; ++r)
        out[(long)(n0 + ty + r * 8) * K + k0 + tx] = f2bf(tile[tx][ty + r * 8]);
}

__global__ __launch_bounds__(256)
void prep(const float* __restrict__ feats, unsigned short* __restrict__ featsb,
          unsigned short* __restrict__ featsbT,
          const float* __restrict__ W_theta, const float* __restrict__ W_phi,
          const float* __restrict__ W_gcn,
          unsigned short* __restrict__ Wtp, unsigned short* __restrict__ Wgt,
          const float* __restrict__ bt, const float* __restrict__ bp,
          float* __restrict__ bias512) {
    __shared__ unsigned short tileT[64][80];   // transposed bf16 tile, 160B row (16B-mult)
    __shared__ float tile[32][33];
    const int bid = blockIdx.x;
    const int t   = threadIdx.x;
    if (bid < 8192) {
        // 64 i-rows x 64 g-cols tile of feats [32768][1024]
        const int i0 = (bid >> 4) * 64, g0 = (bid & 15) * 64;
        const int tx = t & 15;       // g-chunk of 4
        const int ty = t >> 4;       // 16 rows per pass
#pragma unroll
        for (int p = 0; p < 4; ++p) {
            const int row = p * 16 + ty;
            f32x4 v = *(const f32x4*)(feats + (long)(i0 + row) * 1024 + g0 + tx * 4);
            u16x4 o;
#pragma unroll
            for (int c = 0; c < 4; ++c) o[c] = f2bf(v[c]);
            *(u16x4*)(featsb + (long)(i0 + row) * 1024 + g0 + tx * 4) = o;
#pragma unroll
            for (int c = 0; c < 4; ++c) tileT[tx * 4 + c][row] = o[c];
        }
        __syncthreads();
        // featsbT [1024][32768]: 4 threads per g-row, 16 ushorts each (2x16B)
        const int gr = t >> 2, c0 = (t & 3) * 16;
        u16x8 w0 = *(const u16x8*)(&tileT[gr][c0]);
        u16x8 w1 = *(const u16x8*)(&tileT[gr][c0 + 8]);
        unsigned short* dst = featsbT + (long)(g0 + gr) * 32768 + i0 + c0;
        *(u16x8*)(dst)     = w0;
        *(u16x8*)(dst + 8) = w1;
    } else if (bid < 8448) {
        int r = bid - 8192;
        tcast_body(W_theta, Wtp, 1024, 256, r & 7, r >> 3, tile);
    } else if (bid < 8704) {
        int r = bid - 8448;
        tcast_body(W_phi, Wtp + 256 * 1024, 1024, 256, r & 7, r >> 3, tile);
    } else if (bid < 9728) {
        int r = bid - 8704;
        tcast_body(W_gcn, Wgt, 1024, 1024, r & 31, r >> 5, tile);
    } else {
        bias512[t]       = bt[t];
        bias512[t + 256] = bp[t];
    }
}

// ---------------- gemm_bt: C[M][N] = act(A[M][K] @ Bt[N][K]^T + bias) ----------------
// Verified m97-class structure (r0/r2: 905 TF at these shapes): 128x128 tile, 4 waves,
// 32 KB LDS -> 4 blocks/CU; inter-block overlap (m114) hides the barrier drain.
// SWIZ: 1 = B-operand reused (mtile fastest); 2 = A-operand reused (ntile fastest).

template<int RELU, int STORE_BF16, int SWIZ, int LOG_FAST>
__global__ __launch_bounds__(256, 4)
void gemm_bt(const unsigned short* __restrict__ A, const unsigned short* __restrict__ Bt,
             const float* __restrict__ bias, void* __restrict__ Cout,
             int M, int N, int K) {
    __shared__ __align__(16) unsigned short As[128 * 64];   // 16 KB
    __shared__ __align__(16) unsigned short Bs[128 * 64];   // 16 KB
    const int t    = threadIdx.x;
    const int lane = t & 63;
    const int w    = t >> 6;
    const int l15  = lane & 15;
    const int q    = lane >> 4;

    long mtile, ntile;
    if (SWIZ == 1) {
        long linear = (long)blockIdx.y * gridDim.x + blockIdx.x;
        int  xcd  = (int)(linear & 7);
        long slot = linear >> 3;
        mtile = slot & ((1 << LOG_FAST) - 1);
        ntile = (long)xcd * (gridDim.y >> 3) + (slot >> LOG_FAST);
    } else if (SWIZ == 2) {
        long linear = (long)blockIdx.y * gridDim.x + blockIdx.x;
        int  xcd  = (int)(linear & 7);
        long slot = linear >> 3;
        ntile = slot & ((1 << LOG_FAST) - 1);
        mtile = (long)xcd * (gridDim.x >> 3) + (slot >> LOG_FAST);
    } else {
        mtile = blockIdx.x; ntile = blockIdx.y;
    }
    const long tileM = mtile * 128;
    const long tileN = ntile * 128;
    const int wm = (w & 1) * 64;
    const int wn = (w >> 1) * 64;

    f32x4 acc[4][4] = {};

    const int rS = t >> 3;                 // 0..31
    const int cS = (t & 7) ^ (rS & 7);     // swizzled global chunk
    const unsigned short* gA = A  + (tileM + rS) * (long)K + cS * 8;
    const unsigned short* gB = Bt + (tileN + rS) * (long)K + cS * 8;

    for (int kt = 0; kt < K; kt += 64) {
        __syncthreads();                 // protect LDS reuse
#pragma unroll
        for (int i = 0; i < 4; ++i) {
            gld_lds16(gA + (long)i * 32 * K + kt, As + (i * 256 + w * 64) * 8);
            gld_lds16(gB + (long)i * 32 * K + kt, Bs + (i * 256 + w * 64) * 8);
        }
        __syncthreads();                 // drain staging (compiler emits vmcnt(0))
#pragma unroll
        for (int ks = 0; ks < 2; ++ks) {
            const int slot = (ks * 4 + q) ^ (l15 & 7);
            bf16x8 af[4], bf[4];
#pragma unroll
            for (int mi = 0; mi < 4; ++mi)
                af[mi] = *(const bf16x8*)(As + (wm + mi * 16 + l15) * 64 + slot * 8);
#pragma unroll
            for (int ni = 0; ni < 4; ++ni)
                bf[ni] = *(const bf16x8*)(Bs + (wn + ni * 16 + l15) * 64 + slot * 8);
#pragma unroll
            for (int mi = 0; mi < 4; ++mi)
#pragma unroll
                for (int ni = 0; ni < 4; ++ni)
                    acc[mi][ni] = __builtin_amdgcn_mfma_f32_16x16x32_bf16(af[mi], bf[ni],
                                                                          acc[mi][ni], 0, 0, 0);
        }
    }

    // epilogue: C/D layout col=lane&15, row=(lane>>4)*4+reg (verified m89/m91)
#pragma unroll
    for (int mi = 0; mi < 4; ++mi) {
#pragma unroll
        for (int ni = 0; ni < 4; ++ni) {
            long row0 = tileM + wm + mi * 16 + q * 4;
            long col  = tileN + wn + ni * 16 + l15;
            float bv = bias ? bias[col] : 0.f;
#pragma unroll
            for (int r = 0; r < 4; ++r) {
                float v = acc[mi][ni][r] + bv;
                if (RELU) v = fmaxf(v, 0.f);
                long idx = (row0 + r) * N + col;
                if (STORE_BF16) ((unsigned short*)Cout)[idx] = f2bf(v);
                else            ((float*)Cout)[idx] = v;
            }
        }
    }
}

// ---------------- fused: sim -> mask -> softmax -> rg + agg = P @ feats ----------------
// Zero-barrier wave-autonomous (r4). Block = (b, gh); wave w owns rows w*16..+15
// end-to-end. B-frags now come from featsbT [1024 g][32768 i] (same access pattern
// as the old HtT). Output is agg = P @ feats in bf16 (64 MB) — the 128 MB f32 out
// write moves to the compute-bound gemm3 (reassociation: out = relu((P@feats)@Wgcn)).

__global__ __launch_bounds__(256, 4)
void fused_softmax_agg(const unsigned short* __restrict__ thetaphi,  // [32768][512] bf16
                       const float* __restrict__ boxes,              // [512][64][4]
                       const unsigned short* __restrict__ fT,        // [1024][32768] bf16
                       float* __restrict__ rg_out,                   // relation_graph f32
                       unsigned short* __restrict__ agg) {           // [32768][1024] bf16
    __shared__ __align__(16) float sim_s[64][68];
    __shared__ __align__(16) unsigned short Pb[64][72];   // 144B row stride
    const int t    = threadIdx.x;
    const int b    = blockIdx.x >> 1;
    const int gh   = blockIdx.x & 1;
    const int lane = t & 63;
    const int w    = t >> 6;
    const int l15  = lane & 15;
    const int q    = lane >> 4;

    // ---- rolling fT prefetch: slots 0..5 issued before any compute ----
    const unsigned short* fTB = fT + (long)b * 64;        // column offset
    bf16x8 hb0[6], hb1[6];
#pragma unroll
    for (int nt = 0; nt < 6; ++nt) {
        const int g0 = gh * 512 + nt * 16;
        const unsigned short* hp = fTB + (long)(g0 + l15) * 32768 + q * 8;
        hb0[nt] = *(const bf16x8*)(hp);        // j = q*8..q*8+7
        hb1[nt] = *(const bf16x8*)(hp + 32);   // j = 32+q*8..
    }
    __builtin_amdgcn_sched_barrier(0);         // pin prefetch issue before compute

    // box centers in registers: lane ln holds box ln
    float cx, cy;
    {
        float4 bx = *(const float4*)(boxes + ((long)b * 64 + lane) * 4);
        cx = (bx.x + bx.z) * 0.5f;
        cy = (bx.y + bx.w) * 0.5f;
    }

    // sim[i][j] = theta_i . phi_j / 16 ; wave w produces rows w*16..w*16+15
    {
        f32x4 acc[4] = {};
        const unsigned short* thA = thetaphi + ((long)b * 64 + w * 16 + l15) * 512 + q * 8;
        const unsigned short* thB = thetaphi + ((long)b * 64 + l15) * 512 + 256 + q * 8;
#pragma unroll
        for (int kt = 0; kt < 256; kt += 32) {
            bf16x8 a = *(const bf16x8*)(thA + kt);
#pragma unroll
            for (int ni = 0; ni < 4; ++ni) {
                bf16x8 bb = *(const bf16x8*)(thB + (long)ni * 16 * 512 + kt);
                acc[ni] = __builtin_amdgcn_mfma_f32_16x16x32_bf16(a, bb, acc[ni], 0, 0, 0);
            }
        }
#pragma unroll
        for (int ni = 0; ni < 4; ++ni)
#pragma unroll
            for (int r = 0; r < 4; ++r)
                sim_s[w * 16 + q * 4 + r][ni * 16 + l15] = acc[ni][r] * 0.0625f;
    }
    wave_fence();   // intra-wave sim_s handoff

    // softmax row i = t>>2 (in wave w's row range), 4 lanes/row, 16 cols each
    {
        const int i  = t >> 2;
        const int j0 = (t & 3) * 16;
        const float cxi = __shfl(cx, i & 63, 64);
        const float cyi = __shfl(cy, i & 63, 64);
        const float thr = (float)(0.2 * 157.0);
        float vals[16];
        float mx = -__builtin_inff();
#pragma unroll
        for (int jj = 0; jj < 16; ++jj) {
            int j = j0 + jj;
            float dx = cxi - __shfl(cx, j, 64);
            float dy = cyi - __shfl(cy, j, 64);
            bool msk = sqrtf(dx * dx + dy * dy) > thr;
            float s = msk ? -__builtin_inff() : sim_s[i][j];
            vals[jj] = s;
            mx = fmaxf(mx, s);
        }
        mx = fmaxf(mx, __shfl_xor(mx, 1, 64));
        mx = fmaxf(mx, __shfl_xor(mx, 2, 64));
        float sum = 0.f;
#pragma unroll
        for (int jj = 0; jj < 16; ++jj) {
            float e = (vals[jj] == -__builtin_inff()) ? 0.f : __expf(vals[jj] - mx);
            vals[jj] = e;
            sum += e;
        }
        sum += __shfl_xor(sum, 1, 64);
        sum += __shfl_xor(sum, 2, 64);
        float inv = 1.f / sum;   // self always unmasked -> sum > 0
        f32x4 pv[4];
#pragma unroll
        for (int jj = 0; jj < 16; ++jj) {
            float p = vals[jj] * inv;
            pv[jj >> 2][jj & 3] = p;
            Pb[i][j0 + jj] = f2bf(p);
        }
        if (gh == 0) {
            float* rgR = rg_out + ((long)b * 64 + i) * 64 + j0;
#pragma unroll
            for (int c = 0; c < 4; ++c) *(f32x4*)(rgR + c * 4) = pv[c];
        }
    }
    wave_fence();   // intra-wave Pb handoff

    // agg[i][g] = sum_j P[i][j] * feats[j][g]; wave w: rows w*16..+15,
    // g sweeps the gh half (32 nt of 16 g). bf16 store, NO relu (moved to gemm3).
    {
        bf16x8 af0 = *(const bf16x8*)(&Pb[w * 16 + l15][q * 8]);
        bf16x8 af1 = *(const bf16x8*)(&Pb[w * 16 + l15][32 + q * 8]);
        unsigned short* aggR = agg + (long)b * 65536 + (long)(w * 16 + q * 4) * 1024
                                   + gh * 512 + l15;
#pragma unroll
        for (int nt = 0; nt < 32; ++nt) {
            const int s = nt % 6;
            f32x4 acc = {};
            acc = __builtin_amdgcn_mfma_f32_16x16x32_bf16(af0, hb0[s], acc, 0, 0, 0);
            acc = __builtin_amdgcn_mfma_f32_16x16x32_bf16(af1, hb1[s], acc, 0, 0, 0);
            if (nt + 6 < 32) {                    // refill consumed slot (static idx)
                const int g0 = gh * 512 + (nt + 6) * 16;
                const unsigned short* hp = fTB + (long)(g0 + l15) * 32768 + q * 8;
                hb0[s] = *(const bf16x8*)(hp);
                hb1[s] = *(const bf16x8*)(hp + 32);
            }
#pragma unroll
            for (int r = 0; r < 4; ++r)
                aggR[(long)r * 1024 + nt * 16] = f2bf(acc[r]);
        }
    }
}

// ---------------- launch ----------------

extern "C" void kernel_launch(void* const* d_in, const int* in_sizes, int n_in,
                              void* d_out, int out_size, void* d_ws, size_t ws_size,
                              hipStream_t stream) {
    const float* feats   = (const float*)d_in[0];
    const float* boxes   = (const float*)d_in[1];
    const float* W_theta = (const float*)d_in[2];
    const float* b_theta = (const float*)d_in[3];
    const float* W_phi   = (const float*)d_in[4];
    const float* b_phi   = (const float*)d_in[5];
    const float* W_gcn   = (const float*)d_in[6];
    float* out = (float*)d_out;

    // workspace layout (~238 MB; harness fills indicate >=544 MB available)
    char* ws = (char*)d_ws;
    unsigned short* featsb   = (unsigned short*)(ws);                // 67108864 B
    unsigned short* thetaphi = (unsigned short*)(ws + 67108864);     // 33554432 B
    unsigned short* featsbT  = (unsigned short*)(ws + 100663296);    // 67108864 B
    unsigned short* agg      = (unsigned short*)(ws + 167772160);    // 67108864 B
    unsigned short* Wtp      = (unsigned short*)(ws + 234881024);    //  1048576 B
    unsigned short* Wgt      = (unsigned short*)(ws + 235929600);    //  2097152 B
    float*          bias512  = (float*)(ws + 238026752);             //     2048 B

    // dual cast (+transpose) + weight transposes + bias, one launch
    prep<<<9729, 256, 0, stream>>>(feats, featsb, featsbT, W_theta, W_phi, W_gcn,
                                   Wtp, Wgt, b_theta, b_phi, bias512);

    // theta|phi: [32768][512] bf16. A=featsb reused by 4 ntiles -> SWIZ=2
    gemm_bt<0, 1, 2, 2><<<dim3(256, 4), 256, 0, stream>>>(featsb, Wtp, bias512, thetaphi,
                                                          MM, 512, 1024);
    // relation graph + agg = P @ feats (bf16), g-split x2, zero-barrier
    fused_softmax_agg<<<BB * 2, 256, 0, stream>>>(thetaphi, boxes, featsbT,
                                                  out + RG_OFF, agg);
    // out = relu(agg @ Wgcn): M=32768, N=1024, K=1024, f32 out.
    // A=agg reused by 8 ntiles -> SWIZ=2, LOG_FAST=log2(8)=3
    gemm_bt<1, 0, 2, 3><<<dim3(256, 8), 256, 0, stream>>>(agg, Wgt, nullptr, out,
                                                          MM, 1024, 1024);
}